// Round 13
// baseline (678.109 us; speedup 1.0000x reference)
//
#include <hip/hip_runtime.h>
#include <hip/hip_bf16.h>
#include <stdint.h>

#define NE 128
#define NI 1856
#define NKK 6
#define NH 512
#define NT 4096
#define CAP 320
#define NPAIR (NT*NKK)
#define LD2I (2*NI)

typedef unsigned short u16;
typedef __attribute__((ext_vector_type(4))) float f32x4;
typedef __attribute__((ext_vector_type(8))) short bf16x8;
typedef __attribute__((ext_vector_type(4))) short s16x4;
typedef const void __attribute__((address_space(1)))* gas1p;
typedef void __attribute__((address_space(3)))* gas3p;

#define SFENCE __builtin_amdgcn_sched_barrier(0)

__device__ __forceinline__ short f2bf(float f) {
  union { __hip_bfloat16 h; short s; } c; c.h = __float2bfloat16(f); return c.s;
}
__device__ __forceinline__ float bf2f(short s) {
  union { float f; unsigned u; } v; v.u = ((unsigned)(u16)s) << 16; return v.f;
}

// physical bid -> logical L clustering consecutive L on one XCD (bijective any n)
__device__ __forceinline__ int xcd_logical(int bid, int n) {
  int q = n >> 3, r = n & 7;
  int xcd = bid & 7, j = bid >> 3;
  return xcd * q + (xcd < r ? xcd : r) + j;
}

// ---------------- routing ----------------
__global__ void k_route(const int* __restrict__ topk, int* __restrict__ counts,
                        int* __restrict__ slot_of_pair, int* __restrict__ pair_of_slot) {
  int n = blockIdx.x * 256 + threadIdx.x;
  if (n >= NPAIR) return;
  int e = topk[n];
  int p = atomicAdd(&counts[e], 1);
  int s = (p < CAP) ? e * CAP + p : -1;
  slot_of_pair[n] = s;
  if (s >= 0) pair_of_slot[s] = n;
}

// ---------------- gather: hidden(f32) -> Xbuf(bf16) ----------------
__global__ void k_gather(const float* __restrict__ hid, const int* __restrict__ counts,
                         const int* __restrict__ pair_of_slot, u16* __restrict__ xbuf) {
  int t = threadIdx.x;
  int row = blockIdx.x * 2 + (t >> 7);
  int c = t & 127;
  int e = row / CAP, p = row % CAP;
  if (p >= counts[e]) return;
  int n = pair_of_slot[row];
  int tok = n / NKK;
  f32x4 v = *(const f32x4*)(hid + (size_t)tok * NH + c * 4);
  s16x4 o;
  o[0] = f2bf(v[0]); o[1] = f2bf(v[1]); o[2] = f2bf(v[2]); o[3] = f2bf(v[3]);
  *(s16x4*)(xbuf + (size_t)row * NH + c * 4) = o;
}

// ======================= GEMM1 =======================
// X[<=256,512]bf16 @ Wgu[512, 64gate+64up]f32 -> silu*up -> inter bf16
// 256 thr (4 waves 2Mx2N), BK=32, KT=16, nt=29 (64 inter cols / block).
// LDS 80KB: A dbuf 2x16KB @0 (staged 1-ahead, L2-resident), B 3x16KB @32768
// (staged 2-ahead). B rows fetched 512B-contiguous. Per wave per iter:
// 4 A-glld then 4 B-glld; end-of-iter vmcnt(4) drains B(X+1)+A(X+1) (in-order),
// leaves B(X+2) in flight.
__global__ __launch_bounds__(256, 2) void k_gemm1(
    const u16* __restrict__ xbuf, const float* __restrict__ wgu,
    const int* __restrict__ counts, u16* __restrict__ inter, int e0, int nblk)
{
  __shared__ __align__(16) char lds[81920];
  int L = xcd_logical(blockIdx.x, nblk);
  int el = L / 29, nt = L % 29;
  int e = e0 + el;
  int cnt = counts[e]; if (cnt > CAP) cnt = CAP;
  int n0 = nt * 64;                         // inter col base (64 cols)
  int t = threadIdx.x, w = t >> 6, l = t & 63;
  int wm = w >> 1, wc = w & 1;
  const char* abase = (const char*)(xbuf + (size_t)e * CAP * NH);

  // B stage: per instr = 2 rows x 512B; lane: row=(l>>5), chunk=(l&31)*16B
  int ch = l & 31;
  int gc = (ch < 16) ? (n0 + ch * 4) : (NI + n0 + (ch - 16) * 4);
  const float* bsrc0 = wgu + (size_t)e * NH * LD2I + gc + (size_t)(l >> 5) * LD2I;

  int kg = l >> 4, kg16 = kg * 16;
  int colg = wc * 32 + (l & 15);            // gate col (+16 for nf=1); up = +256B

  for (int base = 0; base < cnt; base += 256) {
    __syncthreads();

    auto STAGE_A = [&](int buf, int kt) {
      char* ad = lds + buf * 16384;
      #pragma unroll
      for (int i = 0; i < 4; ++i) {
        int seg = i * 4 + w;
        int o = seg * 1024 + l * 16;
        int r = o >> 6, slot = o & 63;
        int grow = base + r; if (grow > CAP - 1) grow = CAP - 1;
        const char* g = abase + (size_t)grow * (NH * 2) + kt * 64 + (slot ^ ((r & 3) << 4));
        __builtin_amdgcn_global_load_lds((gas1p)g, (gas3p)(ad + seg * 1024), 16, 0, 0);
      }
    };
    auto STAGE_B = [&](int buf, int kt) {
      char* bd = lds + 32768 + buf * 16384;
      #pragma unroll
      for (int i = 0; i < 4; ++i) {
        int seg = w * 4 + i;                       // 0..15; rows 2seg,2seg+1
        const char* g = (const char*)(bsrc0 + (size_t)(kt * 32 + seg * 2) * LD2I);
        __builtin_amdgcn_global_load_lds((gas1p)g, (gas3p)(bd + seg * 1024), 16, 0, 0);
      }
    };

    f32x4 ag[2][4][2], au[2][4][2];
    #pragma unroll
    for (int m = 0; m < 2; ++m)
      #pragma unroll
      for (int f = 0; f < 4; ++f)
        #pragma unroll
        for (int n = 0; n < 2; ++n) { ag[m][f][n] = (f32x4){0,0,0,0}; au[m][f][n] = (f32x4){0,0,0,0}; }

    // prologue: A0, B0, B1 -> vmcnt(4) drains A0,B0 (in-order), leaves B1
    STAGE_A(0, 0);
    STAGE_B(0, 0);
    STAGE_B(1, 1);
    SFENCE; asm volatile("s_waitcnt vmcnt(4) lgkmcnt(0)" ::: "memory"); SFENCE;

    for (int kt = 0; kt < 16; ++kt) {
      SFENCE; __builtin_amdgcn_s_barrier(); SFENCE;
      int ak = (kt + 1 < 16) ? kt + 1 : 15;
      int sk = (kt + 2 < 16) ? kt + 2 : 15;
      STAGE_A((kt + 1) & 1, ak);                  // issued first (drained this iter)
      STAGE_B((kt + 2) % 3, sk);                  // stays in flight across barrier

      const char* ab = lds + (kt & 1) * 16384;
      const char* bb = lds + 32768 + (kt % 3) * 16384;
      bf16x8 bg[2], bu[2];
      #pragma unroll
      for (int nf = 0; nf < 2; ++nf)
        #pragma unroll
        for (int j = 0; j < 8; ++j) {
          int k = kg * 8 + j;
          int c = colg + nf * 16;
          bg[nf][j] = f2bf(*(const float*)(bb + k * 512 + c * 4));
          bu[nf][j] = f2bf(*(const float*)(bb + k * 512 + 256 + c * 4));
        }
      #pragma unroll
      for (int mt = 0; mt < 2; ++mt)
        #pragma unroll
        for (int mf = 0; mf < 4; ++mf) {
          int r = mt * 128 + wm * 64 + mf * 16 + (l & 15);
          bf16x8 af = *(const bf16x8*)(ab + r * 64 + (kg16 ^ ((r & 3) << 4)));
          #pragma unroll
          for (int nf = 0; nf < 2; ++nf) {
            ag[mt][mf][nf] = __builtin_amdgcn_mfma_f32_16x16x32_bf16(af, bg[nf], ag[mt][mf][nf], 0, 0, 0);
            au[mt][mf][nf] = __builtin_amdgcn_mfma_f32_16x16x32_bf16(af, bu[nf], au[mt][mf][nf], 0, 0, 0);
          }
        }
      SFENCE; asm volatile("s_waitcnt vmcnt(4) lgkmcnt(0)" ::: "memory"); SFENCE;
    }
    __syncthreads();   // full drain; all frag reads done before LDS reuse

    // epilogue: silu(g)*u -> repack 256 rows x 128B -> coalesced stores
    #pragma unroll
    for (int mt = 0; mt < 2; ++mt)
      #pragma unroll
      for (int mf = 0; mf < 4; ++mf)
        #pragma unroll
        for (int nf = 0; nf < 2; ++nf) {
          f32x4 g = ag[mt][mf][nf], u = au[mt][mf][nf];
          int cl = wc * 32 + nf * 16 + (l & 15);
          #pragma unroll
          for (int r = 0; r < 4; ++r) {
            float gv = g[r];
            float val = gv / (1.f + __expf(-gv)) * u[r];
            int rl = mt * 128 + wm * 64 + mf * 16 + (l >> 4) * 4 + r;
            *(short*)(lds + rl * 128 + ((cl * 2) ^ ((rl & 7) << 4))) = f2bf(val);
          }
        }
    __syncthreads();
    int rmax = cnt - base; if (rmax > 256) rmax = 256;
    u16* obase = inter + (size_t)(el * CAP + base) * NI + n0;
    #pragma unroll
    for (int i = 0; i < 8; ++i) {
      int task = i * 256 + t;                 // 2048 tasks = 256 rows x 8 parts
      int r = task >> 3, p = task & 7;
      if (r < rmax) {
        bf16x8 v = *(const bf16x8*)(lds + r * 128 + ((p * 16) ^ ((r & 7) << 4)));
        *(bf16x8*)(obase + (size_t)r * NI + p * 8) = v;
      }
    }
  }
}

// ======================= GEMM2 =======================
// inter[<=256,1856]bf16 @ Wdn[1856,128]f32 -> Y bf16; KT=58, nt=4, same pipeline
__global__ __launch_bounds__(256, 2) void k_gemm2(
    const u16* __restrict__ inter, const float* __restrict__ wdn,
    const int* __restrict__ counts, u16* __restrict__ Y, int e0, int nblk)
{
  __shared__ __align__(16) char lds[81920];
  int L = xcd_logical(blockIdx.x, nblk);
  int el = L / 4, nt = L % 4;
  int e = e0 + el;
  int cnt = counts[e]; if (cnt > CAP) cnt = CAP;
  int n0 = nt * 128;                        // out col base (128 cols)
  int t = threadIdx.x, w = t >> 6, l = t & 63;
  int wm = w >> 1, wc = w & 1;
  const char* abase = (const char*)(inter + (size_t)el * CAP * NI);

  int ch = l & 31;
  const float* bsrc0 = wdn + (size_t)e * NI * NH + n0 + ch * 4 + (size_t)(l >> 5) * NH;

  int kg = l >> 4, kg16 = kg * 16;
  int col0 = wc * 64 + (l & 15);            // + nf*16, nf=0..3

  for (int base = 0; base < cnt; base += 256) {
    __syncthreads();

    auto STAGE_A = [&](int buf, int kt) {
      char* ad = lds + buf * 16384;
      #pragma unroll
      for (int i = 0; i < 4; ++i) {
        int seg = i * 4 + w;
        int o = seg * 1024 + l * 16;
        int r = o >> 6, slot = o & 63;
        int grow = base + r; if (grow > CAP - 1) grow = CAP - 1;
        const char* g = abase + (size_t)grow * (NI * 2) + kt * 64 + (slot ^ ((r & 3) << 4));
        __builtin_amdgcn_global_load_lds((gas1p)g, (gas3p)(ad + seg * 1024), 16, 0, 0);
      }
    };
    auto STAGE_B = [&](int buf, int kt) {
      char* bd = lds + 32768 + buf * 16384;
      #pragma unroll
      for (int i = 0; i < 4; ++i) {
        int seg = w * 4 + i;
        const char* g = (const char*)(bsrc0 + (size_t)(kt * 32 + seg * 2) * NH);
        __builtin_amdgcn_global_load_lds((gas1p)g, (gas3p)(bd + seg * 1024), 16, 0, 0);
      }
    };

    f32x4 acc[2][4][4];
    #pragma unroll
    for (int m = 0; m < 2; ++m)
      #pragma unroll
      for (int f = 0; f < 4; ++f)
        #pragma unroll
        for (int n = 0; n < 4; ++n) acc[m][f][n] = (f32x4){0,0,0,0};

    STAGE_A(0, 0);
    STAGE_B(0, 0);
    STAGE_B(1, 1);
    SFENCE; asm volatile("s_waitcnt vmcnt(4) lgkmcnt(0)" ::: "memory"); SFENCE;

    for (int kt = 0; kt < 58; ++kt) {
      SFENCE; __builtin_amdgcn_s_barrier(); SFENCE;
      int ak = (kt + 1 < 58) ? kt + 1 : 57;
      int sk = (kt + 2 < 58) ? kt + 2 : 57;
      STAGE_A((kt + 1) & 1, ak);
      STAGE_B((kt + 2) % 3, sk);

      const char* ab = lds + (kt & 1) * 16384;
      const char* bb = lds + 32768 + (kt % 3) * 16384;
      bf16x8 bf[4];
      #pragma unroll
      for (int nf = 0; nf < 4; ++nf)
        #pragma unroll
        for (int j = 0; j < 8; ++j) {
          int k = kg * 8 + j;
          bf[nf][j] = f2bf(*(const float*)(bb + k * 512 + (col0 + nf * 16) * 4));
        }
      #pragma unroll
      for (int mt = 0; mt < 2; ++mt)
        #pragma unroll
        for (int mf = 0; mf < 4; ++mf) {
          int r = mt * 128 + wm * 64 + mf * 16 + (l & 15);
          bf16x8 af = *(const bf16x8*)(ab + r * 64 + (kg16 ^ ((r & 3) << 4)));
          #pragma unroll
          for (int nf = 0; nf < 4; ++nf)
            acc[mt][mf][nf] = __builtin_amdgcn_mfma_f32_16x16x32_bf16(af, bf[nf], acc[mt][mf][nf], 0, 0, 0);
        }
      SFENCE; asm volatile("s_waitcnt vmcnt(4) lgkmcnt(0)" ::: "memory"); SFENCE;
    }
    __syncthreads();

    // repack: 256 rows x 256B (128 cols bf16)
    #pragma unroll
    for (int mt = 0; mt < 2; ++mt)
      #pragma unroll
      for (int mf = 0; mf < 4; ++mf)
        #pragma unroll
        for (int nf = 0; nf < 4; ++nf) {
          f32x4 a = acc[mt][mf][nf];
          int cl = wc * 64 + nf * 16 + (l & 15);
          #pragma unroll
          for (int r = 0; r < 4; ++r) {
            int rl = mt * 128 + wm * 64 + mf * 16 + (l >> 4) * 4 + r;
            *(short*)(lds + rl * 256 + ((cl * 2) ^ ((rl & 7) << 4))) = f2bf(a[r]);
          }
        }
    __syncthreads();
    int rmax = cnt - base; if (rmax > 256) rmax = 256;
    u16* obase = Y + (size_t)(e * CAP + base) * NH + n0;
    #pragma unroll
    for (int i = 0; i < 16; ++i) {
      int task = i * 256 + t;                 // 4096 tasks = 256 rows x 16 parts
      int r = task >> 4, p = task & 15;
      if (r < rmax) {
        bf16x8 v = *(const bf16x8*)(lds + r * 256 + ((p * 16) ^ ((r & 7) << 4)));
        *(bf16x8*)(obase + (size_t)r * NH + p * 8) = v;
      }
    }
  }
}

// ---------------- combine ----------------
__global__ void k_combine(const int* __restrict__ slot_of_pair, const float* __restrict__ wts,
                          const u16* __restrict__ Y, float* __restrict__ out)
{
  int t = threadIdx.x;
  int tok = blockIdx.x * 2 + (t >> 7);
  int c = t & 127;
  f32x4 a = (f32x4){0.f, 0.f, 0.f, 0.f};
  #pragma unroll
  for (int k = 0; k < NKK; ++k) {
    int n = tok * NKK + k;
    int s = slot_of_pair[n];
    if (s >= 0) {
      float wv = wts[n];
      s16x4 y = *(const s16x4*)(Y + (size_t)s * NH + c * 4);
      a[0] += wv * bf2f(y[0]);
      a[1] += wv * bf2f(y[1]);
      a[2] += wv * bf2f(y[2]);
      a[3] += wv * bf2f(y[3]);
    }
  }
  *(f32x4*)(out + (size_t)tok * NH + c * 4) = a;
  *(f32x4*)(out + (size_t)(NT + tok) * NH + c * 4) = a;
}

extern "C" void kernel_launch(void* const* d_in, const int* in_sizes, int n_in,
                              void* d_out, int out_size, void* d_ws, size_t ws_size,
                              hipStream_t stream) {
  const float* hid  = (const float*)d_in[0];
  const int*   topk = (const int*)d_in[1];
  const float* wts  = (const float*)d_in[2];
  const float* wgu  = (const float*)d_in[3];
  const float* wdn  = (const float*)d_in[4];

  char* ws = (char*)d_ws;
  size_t off = 0;
  auto alloc = [&](size_t sz) { char* p = ws + off; off = (off + sz + 255) & ~(size_t)255; return p; };
  int* counts        = (int*)alloc(NE * 4);
  int* slot_of_pair  = (int*)alloc((size_t)NPAIR * 4);
  int* pair_of_slot  = (int*)alloc((size_t)NE * CAP * 4);
  u16* xbuf          = (u16*)alloc((size_t)NE * CAP * NH * 2);
  u16* Y             = (u16*)alloc((size_t)NE * CAP * NH * 2);
  size_t remain = ws_size > off ? ws_size - off : 0;
  size_t per_e = (size_t)CAP * NI * 2;
  int chunkE = (int)(remain / per_e);
  if (chunkE > NE) chunkE = NE;
  if (chunkE < 1) chunkE = 1;
  u16* inter = (u16*)(ws + off);

  hipMemsetAsync(counts, 0, NE * 4, stream);
  k_route<<<NPAIR / 256, 256, 0, stream>>>(topk, counts, slot_of_pair, pair_of_slot);
  k_gather<<<NE * CAP / 2, 256, 0, stream>>>(hid, counts, pair_of_slot, xbuf);
  for (int e0 = 0; e0 < NE; e0 += chunkE) {
    int ce = NE - e0 < chunkE ? NE - e0 : chunkE;
    int nb1 = ce * 29;
    int nb2 = ce * 4;
    k_gemm1<<<nb1, 256, 0, stream>>>(xbuf, wgu, counts, inter, e0, nb1);
    k_gemm2<<<nb2, 256, 0, stream>>>(inter, wdn, counts, Y, e0, nb2);
  }
  k_combine<<<NT / 2, 256, 0, stream>>>(slot_of_pair, wts, Y, (float*)d_out);
}

// Round 14
// 528.444 us; speedup vs baseline: 1.2832x; 1.2832x over previous
//
#include <hip/hip_runtime.h>
#include <hip/hip_bf16.h>
#include <stdint.h>

#define NE 128
#define NI 1856
#define NKK 6
#define NH 512
#define NT 4096
#define CAP 320
#define NPAIR (NT*NKK)
#define LD2I (2*NI)

typedef unsigned short u16;
typedef __attribute__((ext_vector_type(4))) float f32x4;
typedef __attribute__((ext_vector_type(8))) short bf16x8;
typedef __attribute__((ext_vector_type(4))) short s16x4;
typedef const void __attribute__((address_space(1)))* gas1p;
typedef void __attribute__((address_space(3)))* gas3p;

#define SFENCE __builtin_amdgcn_sched_barrier(0)

__device__ __forceinline__ short f2bf(float f) {
  union { __hip_bfloat16 h; short s; } c; c.h = __float2bfloat16(f); return c.s;
}
__device__ __forceinline__ float bf2f(short s) {
  union { float f; unsigned u; } v; v.u = ((unsigned)(u16)s) << 16; return v.f;
}

// physical bid -> logical L clustering consecutive L on one XCD (bijective any n)
__device__ __forceinline__ int xcd_logical(int bid, int n) {
  int q = n >> 3, r = n & 7;
  int xcd = bid & 7, j = bid >> 3;
  return xcd * q + (xcd < r ? xcd : r) + j;
}

// ---------------- routing ----------------
__global__ void k_route(const int* __restrict__ topk, int* __restrict__ counts,
                        int* __restrict__ slot_of_pair, int* __restrict__ pair_of_slot) {
  int n = blockIdx.x * 256 + threadIdx.x;
  if (n >= NPAIR) return;
  int e = topk[n];
  int p = atomicAdd(&counts[e], 1);
  int s = (p < CAP) ? e * CAP + p : -1;
  slot_of_pair[n] = s;
  if (s >= 0) pair_of_slot[s] = n;
}

// ---------------- gather: hidden(f32) -> Xbuf(bf16) ----------------
__global__ void k_gather(const float* __restrict__ hid, const int* __restrict__ counts,
                         const int* __restrict__ pair_of_slot, u16* __restrict__ xbuf) {
  int t = threadIdx.x;
  int row = blockIdx.x * 2 + (t >> 7);
  int c = t & 127;
  int e = row / CAP, p = row % CAP;
  if (p >= counts[e]) return;
  int n = pair_of_slot[row];
  int tok = n / NKK;
  f32x4 v = *(const f32x4*)(hid + (size_t)tok * NH + c * 4);
  s16x4 o;
  o[0] = f2bf(v[0]); o[1] = f2bf(v[1]); o[2] = f2bf(v[2]); o[3] = f2bf(v[3]);
  *(s16x4*)(xbuf + (size_t)row * NH + c * 4) = o;
}

// ======================= GEMM1 =======================
// R12 schedule with deepened prefetch: A tri-buf staged 2-ahead (L2-resident
// xbuf), B quad-buf staged 3-ahead (HBM). Issue per iter: A(X+2)x4, B(X+3)x2.
// FIFO: end-of-iter vmcnt(8) drains B(X+1) (2 iters old) + A(X+1) (1 iter,
// L2) -> steady-state wait bubble ~0. LDS 80KB -> 2 blocks/CU unchanged.
__global__ __launch_bounds__(256, 2) void k_gemm1(
    const u16* __restrict__ xbuf, const float* __restrict__ wgu,
    const int* __restrict__ counts, u16* __restrict__ inter, int e0, int nblk)
{
  __shared__ __align__(16) char lds[81920];   // A: 3x16384 @0; B(f32): 4x8192 @49152
  int L = xcd_logical(blockIdx.x, nblk);
  int el = L / 58, nt = L % 58;
  int e = e0 + el;
  int cnt = counts[e]; if (cnt > CAP) cnt = CAP;
  int n0 = nt * 32;
  int t = threadIdx.x, w = t >> 6, l = t & 63;
  int wm = w >> 1, wc = w & 1;
  const char* abase = (const char*)(xbuf + (size_t)e * CAP * NH);

  // B stage: per-lane global src, swizzled chunk (R12); LDS dest linear
  int bks = l >> 4;
  int csw = ((l & 15) ^ (w << 2)) * 4;
  int gcol = (csw < 32) ? (n0 + csw) : (NI + n0 + (csw - 32));
  const float* bsrc = wgu + (size_t)e * NH * LD2I + gcol;

  int kg = l >> 4;
  int kg16 = kg * 16;
  int colg = wc * 16 + (l & 15);
  int cu = colg + 32;
  int bog = (((colg >> 2) ^ (kg << 2)) << 4) + (colg & 3) * 4;
  int bou = (((cu   >> 2) ^ (kg << 2)) << 4) + (cu   & 3) * 4;

  for (int base = 0; base < cnt; base += 256) {
    __syncthreads();

    auto STAGE_A = [&](int buf, int kt) {
      char* ad = lds + buf * 16384;
      #pragma unroll
      for (int i = 0; i < 4; ++i) {
        int seg = i * 4 + w;
        int o = seg * 1024 + l * 16;
        int r = o >> 6, slot = o & 63;
        int grow = base + r; if (grow > CAP - 1) grow = CAP - 1;
        const char* g = abase + (size_t)grow * (NH * 2) + kt * 64 + (slot ^ ((r & 3) << 4));
        __builtin_amdgcn_global_load_lds((gas1p)g, (gas3p)(ad + seg * 1024), 16, 0, 0);
      }
    };
    auto STAGE_B = [&](int buf, int kt) {
      char* bd = lds + 49152 + buf * 8192;
      #pragma unroll
      for (int i = 0; i < 2; ++i) {
        int seg = w * 2 + i;                       // 0..7 (4 k-rows each)
        int k = seg * 4 + bks;                     // (k>>3)&3 == w
        const char* g = (const char*)(bsrc + (size_t)(kt * 32 + k) * LD2I);
        __builtin_amdgcn_global_load_lds((gas1p)g, (gas3p)(bd + seg * 1024), 16, 0, 0);
      }
    };

    f32x4 acc[2][4][2];
    #pragma unroll
    for (int m = 0; m < 2; ++m)
      #pragma unroll
      for (int f = 0; f < 4; ++f) { acc[m][f][0] = (f32x4){0,0,0,0}; acc[m][f][1] = (f32x4){0,0,0,0}; }

    // prologue FIFO: B0(2), A0(4), B1(2), A1(4), B2(2) = 14; vmcnt(8) pops B0,A0
    STAGE_B(0, 0);
    STAGE_A(0, 0);
    STAGE_B(1, 1);
    STAGE_A(1, 1);
    STAGE_B(2, 2);
    SFENCE; asm volatile("s_waitcnt vmcnt(8) lgkmcnt(0)" ::: "memory"); SFENCE;

    for (int kt = 0; kt < 16; ++kt) {
      SFENCE; __builtin_amdgcn_s_barrier(); SFENCE;
      int ak = (kt + 2 < 16) ? kt + 2 : 15;
      int bk = (kt + 3 < 16) ? kt + 3 : 15;
      STAGE_A((kt + 2) % 3, ak);
      STAGE_B((kt + 3) & 3, bk);

      const char* ab = lds + (kt % 3) * 16384;
      const char* bb = lds + 49152 + (kt & 3) * 8192;
      bf16x8 bg, bu;
      #pragma unroll
      for (int j = 0; j < 8; ++j) {
        int k = kg * 8 + j;
        bg[j] = f2bf(*(const float*)(bb + k * 256 + bog));
        bu[j] = f2bf(*(const float*)(bb + k * 256 + bou));
      }
      #pragma unroll
      for (int mt = 0; mt < 2; ++mt)
        #pragma unroll
        for (int mf = 0; mf < 4; ++mf) {
          int r = mt * 128 + wm * 64 + mf * 16 + (l & 15);
          bf16x8 af = *(const bf16x8*)(ab + r * 64 + (kg16 ^ ((r & 3) << 4)));
          acc[mt][mf][0] = __builtin_amdgcn_mfma_f32_16x16x32_bf16(af, bg, acc[mt][mf][0], 0, 0, 0);
          acc[mt][mf][1] = __builtin_amdgcn_mfma_f32_16x16x32_bf16(af, bu, acc[mt][mf][1], 0, 0, 0);
        }
      SFENCE; asm volatile("s_waitcnt vmcnt(8) lgkmcnt(0)" ::: "memory"); SFENCE;
    }
    __syncthreads();   // full drain; all frag reads done before LDS reuse

    // epilogue: silu(g)*u -> repack rows x 64B -> coalesced stores
    int cl = wc * 16 + (l & 15);
    #pragma unroll
    for (int mt = 0; mt < 2; ++mt)
      #pragma unroll
      for (int mf = 0; mf < 4; ++mf) {
        f32x4 g = acc[mt][mf][0], u = acc[mt][mf][1];
        #pragma unroll
        for (int r = 0; r < 4; ++r) {
          float gv = g[r];
          float val = gv / (1.f + __expf(-gv)) * u[r];
          int rl = mt * 128 + wm * 64 + mf * 16 + (l >> 4) * 4 + r;
          *(short*)(lds + rl * 64 + ((cl * 2) ^ ((rl & 3) << 4))) = f2bf(val);
        }
      }
    __syncthreads();
    int rmax = cnt - base; if (rmax > 256) rmax = 256;
    u16* obase = inter + (size_t)(el * CAP + base) * NI + n0;
    #pragma unroll
    for (int i = 0; i < 4; ++i) {
      int task = i * 256 + t;
      int r = task >> 2, p = task & 3;
      if (r < rmax) {
        bf16x8 v = *(const bf16x8*)(lds + r * 64 + ((p * 16) ^ ((r & 3) << 4)));
        *(bf16x8*)(obase + (size_t)r * NI + p * 8) = v;
      }
    }
  }
}

// ======================= GEMM2 =======================
// inter[<=256,1856]bf16 @ Wdn[1856,64]f32 -> Y bf16; KT=58, same deep pipeline
__global__ __launch_bounds__(256, 2) void k_gemm2(
    const u16* __restrict__ inter, const float* __restrict__ wdn,
    const int* __restrict__ counts, u16* __restrict__ Y, int e0, int nblk)
{
  __shared__ __align__(16) char lds[81920];
  int L = xcd_logical(blockIdx.x, nblk);
  int el = L / 8, nt = L % 8;
  int e = e0 + el;
  int cnt = counts[e]; if (cnt > CAP) cnt = CAP;
  int n0 = nt * 64;
  int t = threadIdx.x, w = t >> 6, l = t & 63;
  int wm = w >> 1, wc = w & 1;
  const char* abase = (const char*)(inter + (size_t)el * CAP * NI);

  int bks = l >> 4;
  int csw = ((l & 15) ^ (w << 2)) * 4;
  const float* bsrc = wdn + (size_t)e * NI * NH + n0 + csw;

  int kg = l >> 4;
  int kg16 = kg * 16;
  int col0 = wc * 32 + (l & 15);
  int col1 = col0 + 16;
  int bo0 = (((col0 >> 2) ^ (kg << 2)) << 4) + (col0 & 3) * 4;
  int bo1 = (((col1 >> 2) ^ (kg << 2)) << 4) + (col1 & 3) * 4;

  for (int base = 0; base < cnt; base += 256) {
    __syncthreads();

    auto STAGE_A = [&](int buf, int kt) {
      char* ad = lds + buf * 16384;
      #pragma unroll
      for (int i = 0; i < 4; ++i) {
        int seg = i * 4 + w;
        int o = seg * 1024 + l * 16;
        int r = o >> 6, slot = o & 63;
        int grow = base + r; if (grow > CAP - 1) grow = CAP - 1;
        const char* g = abase + (size_t)grow * (NI * 2) + kt * 64 + (slot ^ ((r & 3) << 4));
        __builtin_amdgcn_global_load_lds((gas1p)g, (gas3p)(ad + seg * 1024), 16, 0, 0);
      }
    };
    auto STAGE_B = [&](int buf, int kt) {
      char* bd = lds + 49152 + buf * 8192;
      #pragma unroll
      for (int i = 0; i < 2; ++i) {
        int seg = w * 2 + i;
        int k = seg * 4 + bks;
        const char* g = (const char*)(bsrc + (size_t)(kt * 32 + k) * NH);
        __builtin_amdgcn_global_load_lds((gas1p)g, (gas3p)(bd + seg * 1024), 16, 0, 0);
      }
    };

    f32x4 acc[2][4][2];
    #pragma unroll
    for (int m = 0; m < 2; ++m)
      #pragma unroll
      for (int f = 0; f < 4; ++f) { acc[m][f][0] = (f32x4){0,0,0,0}; acc[m][f][1] = (f32x4){0,0,0,0}; }

    STAGE_B(0, 0);
    STAGE_A(0, 0);
    STAGE_B(1, 1);
    STAGE_A(1, 1);
    STAGE_B(2, 2);
    SFENCE; asm volatile("s_waitcnt vmcnt(8) lgkmcnt(0)" ::: "memory"); SFENCE;

    for (int kt = 0; kt < 58; ++kt) {
      SFENCE; __builtin_amdgcn_s_barrier(); SFENCE;
      int ak = (kt + 2 < 58) ? kt + 2 : 57;
      int bk = (kt + 3 < 58) ? kt + 3 : 57;
      STAGE_A((kt + 2) % 3, ak);
      STAGE_B((kt + 3) & 3, bk);

      const char* ab = lds + (kt % 3) * 16384;
      const char* bb = lds + 49152 + (kt & 3) * 8192;
      bf16x8 b0, b1;
      #pragma unroll
      for (int j = 0; j < 8; ++j) {
        int k = kg * 8 + j;
        b0[j] = f2bf(*(const float*)(bb + k * 256 + bo0));
        b1[j] = f2bf(*(const float*)(bb + k * 256 + bo1));
      }
      #pragma unroll
      for (int mt = 0; mt < 2; ++mt)
        #pragma unroll
        for (int mf = 0; mf < 4; ++mf) {
          int r = mt * 128 + wm * 64 + mf * 16 + (l & 15);
          bf16x8 af = *(const bf16x8*)(ab + r * 64 + (kg16 ^ ((r & 3) << 4)));
          acc[mt][mf][0] = __builtin_amdgcn_mfma_f32_16x16x32_bf16(af, b0, acc[mt][mf][0], 0, 0, 0);
          acc[mt][mf][1] = __builtin_amdgcn_mfma_f32_16x16x32_bf16(af, b1, acc[mt][mf][1], 0, 0, 0);
        }
      SFENCE; asm volatile("s_waitcnt vmcnt(8) lgkmcnt(0)" ::: "memory"); SFENCE;
    }
    __syncthreads();

    // repack: 256 rows x 128B (64 cols bf16)
    #pragma unroll
    for (int mt = 0; mt < 2; ++mt)
      #pragma unroll
      for (int mf = 0; mf < 4; ++mf)
        #pragma unroll
        for (int f = 0; f < 2; ++f) {
          f32x4 a = acc[mt][mf][f];
          int cl = wc * 32 + f * 16 + (l & 15);
          #pragma unroll
          for (int r = 0; r < 4; ++r) {
            int rl = mt * 128 + wm * 64 + mf * 16 + (l >> 4) * 4 + r;
            *(short*)(lds + rl * 128 + ((cl * 2) ^ ((rl & 7) << 4))) = f2bf(a[r]);
          }
        }
    __syncthreads();
    int rmax = cnt - base; if (rmax > 256) rmax = 256;
    u16* obase = Y + (size_t)(e * CAP + base) * NH + n0;
    #pragma unroll
    for (int i = 0; i < 8; ++i) {
      int task = i * 256 + t;
      int r = task >> 3, p = task & 7;
      if (r < rmax) {
        bf16x8 v = *(const bf16x8*)(lds + r * 128 + ((p * 16) ^ ((r & 7) << 4)));
        *(bf16x8*)(obase + (size_t)r * NH + p * 8) = v;
      }
    }
  }
}

// ---------------- combine ----------------
__global__ void k_combine(const int* __restrict__ slot_of_pair, const float* __restrict__ wts,
                          const u16* __restrict__ Y, float* __restrict__ out)
{
  int t = threadIdx.x;
  int tok = blockIdx.x * 2 + (t >> 7);
  int c = t & 127;
  f32x4 a = (f32x4){0.f, 0.f, 0.f, 0.f};
  #pragma unroll
  for (int k = 0; k < NKK; ++k) {
    int n = tok * NKK + k;
    int s = slot_of_pair[n];
    if (s >= 0) {
      float wv = wts[n];
      s16x4 y = *(const s16x4*)(Y + (size_t)s * NH + c * 4);
      a[0] += wv * bf2f(y[0]);
      a[1] += wv * bf2f(y[1]);
      a[2] += wv * bf2f(y[2]);
      a[3] += wv * bf2f(y[3]);
    }
  }
  *(f32x4*)(out + (size_t)tok * NH + c * 4) = a;
  *(f32x4*)(out + (size_t)(NT + tok) * NH + c * 4) = a;
}

extern "C" void kernel_launch(void* const* d_in, const int* in_sizes, int n_in,
                              void* d_out, int out_size, void* d_ws, size_t ws_size,
                              hipStream_t stream) {
  const float* hid  = (const float*)d_in[0];
  const int*   topk = (const int*)d_in[1];
  const float* wts  = (const float*)d_in[2];
  const float* wgu  = (const float*)d_in[3];
  const float* wdn  = (const float*)d_in[4];

  char* ws = (char*)d_ws;
  size_t off = 0;
  auto alloc = [&](size_t sz) { char* p = ws + off; off = (off + sz + 255) & ~(size_t)255; return p; };
  int* counts        = (int*)alloc(NE * 4);
  int* slot_of_pair  = (int*)alloc((size_t)NPAIR * 4);
  int* pair_of_slot  = (int*)alloc((size_t)NE * CAP * 4);
  u16* xbuf          = (u16*)alloc((size_t)NE * CAP * NH * 2);
  u16* Y             = (u16*)alloc((size_t)NE * CAP * NH * 2);
  size_t remain = ws_size > off ? ws_size - off : 0;
  size_t per_e = (size_t)CAP * NI * 2;
  int chunkE = (int)(remain / per_e);
  if (chunkE > NE) chunkE = NE;
  if (chunkE < 1) chunkE = 1;
  u16* inter = (u16*)(ws + off);

  hipMemsetAsync(counts, 0, NE * 4, stream);
  k_route<<<NPAIR / 256, 256, 0, stream>>>(topk, counts, slot_of_pair, pair_of_slot);
  k_gather<<<NE * CAP / 2, 256, 0, stream>>>(hid, counts, pair_of_slot, xbuf);
  for (int e0 = 0; e0 < NE; e0 += chunkE) {
    int ce = NE - e0 < chunkE ? NE - e0 : chunkE;
    int nb1 = ce * 58;
    int nb2 = ce * 8;
    k_gemm1<<<nb1, 256, 0, stream>>>(xbuf, wgu, counts, inter, e0, nb1);
    k_gemm2<<<nb2, 256, 0, stream>>>(inter, wdn, counts, Y, e0, nb2);
  }
  k_combine<<<NT / 2, 256, 0, stream>>>(slot_of_pair, wts, Y, (float*)d_out);
}